// Round 2
// baseline (713.556 us; speedup 1.0000x reference)
//
#include <hip/hip_runtime.h>

#define M_OUT   125000
#define CIN     96
#define COUT    192
#define KOCT    8
#define MT      64       // rows per block
#define LDA     104      // padded bf16 stride; 16B-aligned rows, 2-way-bank-free b128 reads
#define BN_EPS  1e-5f

// ws layout (floats at base):
//   [0,192) sums   [192,384) sumsq   [384,576) scale   [576,768) shift
// byte 4096: bf16 WT[k][n][c_pad104]  (8*192*104*2 = 319488 B)
#define WS_SCALE_OFF 384
#define WS_WT_BYTE   4096

typedef __attribute__((ext_vector_type(8))) short bf16x8;
typedef __attribute__((ext_vector_type(4))) float f32x4;

__device__ __forceinline__ unsigned short f2bf(float f) {
    unsigned int u = __float_as_uint(f);
    u += 0x7FFF + ((u >> 16) & 1);           // RNE
    return (unsigned short)(u >> 16);
}

__device__ __forceinline__ unsigned int pack2(float a, float b) {
    unsigned int ua = __float_as_uint(a);
    unsigned int ub = __float_as_uint(b);
    ua += 0x7FFF + ((ua >> 16) & 1);
    ub += 0x7FFF + ((ub >> 16) & 1);
    return (ua >> 16) | (ub & 0xFFFF0000u);
}

// ---------------- prep: zero stats + build bf16 transposed padded weights ----
__global__ void prep_kernel(const float* __restrict__ W, float* __restrict__ ws_f,
                            unsigned short* __restrict__ wt) {
    int gid = blockIdx.x * blockDim.x + threadIdx.x;
    if (gid < 384) ws_f[gid] = 0.0f;
    if (gid < KOCT * COUT * LDA) {
        int c = gid % LDA;
        int rest = gid / LDA;
        int n = rest % COUT;
        int k = rest / COUT;
        float v = (c < CIN) ? W[(k * CIN + c) * COUT + n] : 0.0f;
        wt[gid] = f2bf(v);
    }
}

// ---------------- conv: gather-GEMM, dbuf A-stage, B direct from L2 ----------
__global__ __launch_bounds__(256, 3)
void conv_kernel(const float* __restrict__ data,
                 const int* __restrict__ neigh,
                 const float* __restrict__ bias,
                 const unsigned short* __restrict__ wt,
                 float* __restrict__ out,
                 float* __restrict__ gsum) {
    __shared__ alignas(16) unsigned short As[2][MT * LDA];   // 2 x 13312 B

    const int t    = threadIdx.x;
    const int lane = t & 63;
    const int w    = t >> 6;       // wave 0..3 -> col group w*48
    const int quad = lane >> 4;
    const int l15  = lane & 15;
    const int grow = t >> 2;       // gather row 0..63 (4 threads per row)
    const int qt   = t & 3;        // float4 slot within row: f4 = qt + 4i
    const int m0   = blockIdx.x * MT;

    // per-thread neighbor indices for its gather row (all 8 octants)
    int idx8[8];
    {
        int gm = m0 + grow;
        if (gm < M_OUT) {
            int4 a = *reinterpret_cast<const int4*>(neigh + (size_t)gm * 8);
            int4 b = *reinterpret_cast<const int4*>(neigh + (size_t)gm * 8 + 4);
            idx8[0] = a.x; idx8[1] = a.y; idx8[2] = a.z; idx8[3] = a.w;
            idx8[4] = b.x; idx8[5] = b.y; idx8[6] = b.z; idx8[7] = b.w;
        } else {
#pragma unroll
            for (int i = 0; i < 8; ++i) idx8[i] = -1;
        }
    }

    const f32x4 vzero = {0.f, 0.f, 0.f, 0.f};
    const float4 fzero = {0.f, 0.f, 0.f, 0.f};
    f32x4 acc[4][3];
#pragma unroll
    for (int i = 0; i < 4; ++i)
#pragma unroll
        for (int j = 0; j < 3; ++j) acc[i][j] = vzero;

    // ---- prologue: gather octant 0 into buf 0
    {
        int idx = idx8[0];
        const float4* src = reinterpret_cast<const float4*>(
                                data + (size_t)(idx < 0 ? 0 : idx) * CIN) + qt;
#pragma unroll
        for (int i = 0; i < 6; ++i) {
            float4 g = (idx >= 0) ? src[i * 4] : fzero;
            uint2 p; p.x = pack2(g.x, g.y); p.y = pack2(g.z, g.w);
            *reinterpret_cast<uint2*>(&As[0][grow * LDA + (qt + 4 * i) * 4]) = p;
        }
    }
    __syncthreads();

    for (int k = 0; k < KOCT; ++k) {
        const int buf = k & 1;

        // 1. B fragments for this octant — issue FIRST (vmcnt order: waiting on
        //    these must NOT drain the gather loads issued after)
        bf16x8 bfr[3][3];
#pragma unroll
        for (int ks = 0; ks < 3; ++ks)
#pragma unroll
            for (int ct = 0; ct < 3; ++ct) {
                int col = w * 48 + ct * 16 + l15;
                bfr[ks][ct] = *reinterpret_cast<const bf16x8*>(
                    wt + ((size_t)k * COUT + col) * LDA + ks * 32 + quad * 8);
            }

        // 2. gather loads for octant k+1 — long-latency, ride under the MFMAs
        float4 g[6];
        int idxn = (k < KOCT - 1) ? idx8[k + 1] : -1;
        {
            const float4* srcn = reinterpret_cast<const float4*>(
                                     data + (size_t)(idxn < 0 ? 0 : idxn) * CIN) + qt;
#pragma unroll
            for (int i = 0; i < 6; ++i) g[i] = (idxn >= 0) ? srcn[i * 4] : fzero;
        }

        // 3. MFMA phase on buf (A frags via lgkmcnt — independent of vmcnt)
#pragma unroll
        for (int ks = 0; ks < 3; ++ks) {
            bf16x8 af[4];
#pragma unroll
            for (int rt = 0; rt < 4; ++rt)
                af[rt] = *reinterpret_cast<const bf16x8*>(
                    &As[buf][(rt * 16 + l15) * LDA + ks * 32 + quad * 8]);
#pragma unroll
            for (int rt = 0; rt < 4; ++rt)
#pragma unroll
                for (int ct = 0; ct < 3; ++ct)
                    acc[rt][ct] = __builtin_amdgcn_mfma_f32_16x16x32_bf16(
                        af[rt], bfr[ks][ct], acc[rt][ct], 0, 0, 0);
        }

        // 4. stage octant k+1 into the other buffer
        if (k < KOCT - 1) {
#pragma unroll
            for (int i = 0; i < 6; ++i) {
                uint2 p; p.x = pack2(g[i].x, g[i].y); p.y = pack2(g[i].z, g[i].w);
                *reinterpret_cast<uint2*>(&As[buf ^ 1][grow * LDA + (qt + 4 * i) * 4]) = p;
            }
        }
        __syncthreads();
    }

    // ---- epilogue: + bias, store conv-out fp32, per-channel sum/sumsq
#pragma unroll
    for (int ct = 0; ct < 3; ++ct) {
        int col = w * 48 + ct * 16 + l15;
        float b = bias[col];
        float s1 = 0.f, s2 = 0.f;
#pragma unroll
        for (int rt = 0; rt < 4; ++rt) {
#pragma unroll
            for (int r = 0; r < 4; ++r) {
                int gm = m0 + rt * 16 + quad * 4 + r;
                if (gm < M_OUT) {
                    float v = acc[rt][ct][r] + b;
                    out[(size_t)gm * COUT + col] = v;
                    s1 += v;
                    s2 += v * v;
                }
            }
        }
        // quad-reduce (each col owned by exactly one wave; 4 quads hold its rows)
        s1 += __shfl_xor(s1, 16); s1 += __shfl_xor(s1, 32);
        s2 += __shfl_xor(s2, 16); s2 += __shfl_xor(s2, 32);
        if (quad == 0) {
            atomicAdd(&gsum[col], s1);
            atomicAdd(&gsum[COUT + col], s2);
        }
    }
}

// ---------------- finalize: per-channel scale/shift -------------------------
__global__ void finalize_kernel(const float* __restrict__ gsum,
                                const float* __restrict__ gamma,
                                const float* __restrict__ beta,
                                float* __restrict__ ss) {
    int c = threadIdx.x;
    if (c < COUT) {
        float inv_m = 1.0f / (float)M_OUT;
        float mean = gsum[c] * inv_m;
        float var  = gsum[COUT + c] * inv_m - mean * mean;
        float rstd = rsqrtf(var + BN_EPS);
        float sc   = gamma[c] * rstd;
        ss[c]        = sc;
        ss[COUT + c] = beta[c] - mean * sc;
    }
}

// ---------------- normalize: y = x*scale[c] + shift[c] ----------------------
__global__ void norm_kernel(float* __restrict__ out, const float* __restrict__ ss) {
    __shared__ float s_scale[COUT], s_shift[COUT];
    for (int i = threadIdx.x; i < COUT; i += blockDim.x) {
        s_scale[i] = ss[i];
        s_shift[i] = ss[COUT + i];
    }
    __syncthreads();
    const int total4 = M_OUT * COUT / 4;   // 6,000,000
    int stride = gridDim.x * blockDim.x;
    for (int i = blockIdx.x * blockDim.x + threadIdx.x; i < total4; i += stride) {
        float4 v = reinterpret_cast<float4*>(out)[i];
        int c4 = (i % (COUT / 4)) * 4;
        v.x = v.x * s_scale[c4 + 0] + s_shift[c4 + 0];
        v.y = v.y * s_scale[c4 + 1] + s_shift[c4 + 1];
        v.z = v.z * s_scale[c4 + 2] + s_shift[c4 + 2];
        v.w = v.w * s_scale[c4 + 3] + s_shift[c4 + 3];
        reinterpret_cast<float4*>(out)[i] = v;
    }
}

extern "C" void kernel_launch(void* const* d_in, const int* in_sizes, int n_in,
                              void* d_out, int out_size, void* d_ws, size_t ws_size,
                              hipStream_t stream) {
    const float* data  = (const float*)d_in[0];
    const float* W     = (const float*)d_in[1];
    const float* bias  = (const float*)d_in[2];
    const float* gamma = (const float*)d_in[3];
    const float* beta  = (const float*)d_in[4];
    const int*   neigh = (const int*)d_in[5];
    float* out  = (float*)d_out;
    float* ws_f = (float*)d_ws;
    unsigned short* wt = (unsigned short*)((char*)d_ws + WS_WT_BYTE);

    // 1. prep: zero stats, build bf16 weights
    prep_kernel<<<(KOCT * COUT * LDA + 255) / 256, 256, 0, stream>>>(W, ws_f, wt);

    // 2. gather-GEMM conv + stat accumulation
    int grid1 = (M_OUT + MT - 1) / MT;   // 1954
    conv_kernel<<<grid1, 256, 0, stream>>>(data, neigh, bias, wt, out, ws_f);

    // 3. per-channel scale/shift
    finalize_kernel<<<1, 192, 0, stream>>>(ws_f, gamma, beta, ws_f + WS_SCALE_OFF);

    // 4. in-place normalize
    norm_kernel<<<4096, 256, 0, stream>>>(out, ws_f + WS_SCALE_OFF);
}